// Round 11
// baseline (62.465 us; speedup 1.0000x reference)
//
#include <hip/hip_runtime.h>
#include <hip/hip_bf16.h>
#include <hip/hip_fp16.h>
#include <stdint.h>

#define B_ROWS 2048
#define FEAT   2048
#define NK     128
#define ND     16
#define NCOL   2048   // NK*ND

#define BM 128
#define BN 128
#define BK 64

typedef __attribute__((ext_vector_type(4))) float    f32x4;
typedef __attribute__((ext_vector_type(8)))  _Float16 f16x8;
typedef __attribute__((ext_vector_type(4)))  _Float16 f16x4;
typedef __attribute__((ext_vector_type(2)))  _Float16 f16x2;

__device__ __forceinline__ f16x2 u2h(unsigned u) { return __builtin_bit_cast(f16x2, u); }
__device__ __forceinline__ f16x2 absdiff2(f16x2 a, f16x2 b) {
    f16x2 d = a - b;                       // v_pk_sub_f16
    unsigned u = __builtin_bit_cast(unsigned, d) & 0x7fff7fffu;  // v_and_b32 (abs both halves)
    return __builtin_bit_cast(f16x2, u);
}
// cvt_pkrtz returns __fp16x2; bit_cast to u32 for LDS packing.
__device__ __forceinline__ unsigned pkrtz_u32(float lo, float hi) {
    return __builtin_bit_cast(unsigned, __builtin_amdgcn_cvt_pkrtz(lo, hi));
}

// ------------- Kernel 1: W [k][n] f32 -> Wt [n][k] f16 (transpose only) ---
__global__ __launch_bounds__(256) void k_prep(const float* __restrict__ W,
                                              _Float16* __restrict__ Wt) {
    __shared__ float tile[32][33];
    int bb = blockIdx.x;
    int tid = threadIdx.x;
    int tx = tid & 31, ty = tid >> 5;   // 32 x 8
    int n0 = (bb & 63) * 32, k0 = (bb >> 6) * 32;
    #pragma unroll
    for (int i = 0; i < 4; ++i)
        tile[ty + i * 8][tx] = W[(size_t)(k0 + ty + i * 8) * NCOL + n0 + tx];
    __syncthreads();
    #pragma unroll
    for (int i = 0; i < 4; ++i)
        Wt[(size_t)(n0 + ty + i * 8) * FEAT + k0 + tx] = (_Float16)tile[tx][ty + i * 8];
}

// ---------------- Kernel 2: f16 MFMA GEMM, 2-phase double-buffered --------
// A read DIRECTLY from f32 x: reg-staged (8 global_load_dwordx4 issued
// before compute, vmcnt(0) + v_cvt_pkrtz + 4 ds_write_b128 after compute).
// B staged via global_load_lds. Removes the x->f16 prep pass + HBM trip.
__global__ __launch_bounds__(256) void k_gemm(const float* __restrict__ X,
                                              const _Float16* __restrict__ Bt,
                                              _Float16* __restrict__ Cparts,
                                              int kt_per) {
    __shared__ __align__(16) unsigned short As[2][BM * BK];  // 2 x 16KB
    __shared__ __align__(16) unsigned short Bs[2][BN * BK];  // 2 x 16KB
    const int tid  = threadIdx.x;
    const int wave = tid >> 6;
    const int lane = tid & 63;
    const int bm = blockIdx.y, bn = blockIdx.x, z = blockIdx.z;
    _Float16* C = Cparts + (size_t)z * B_ROWS * NCOL;
    const int wm = (wave >> 1) * 64;
    const int wn = (wave & 1) * 64;

    const int srow  = lane >> 3;        // 0..7: row within 8-row chunk
    const int skcol = (lane & 7) * 8;   // element offset (8 elems per lane)

    const int mrow_s = wave * 32 + srow;                 // + r*8
    const float*    gX0 = X  + (size_t)(bm * BM + mrow_s) * FEAT + skcol;
    const _Float16* gB0 = Bt + (size_t)(bn * BN + mrow_s) * FEAT + skcol;

    f32x4 acc[4][4];
    #pragma unroll
    for (int i = 0; i < 4; ++i)
        #pragma unroll
        for (int j = 0; j < 4; ++j)
            acc[i][j] = (f32x4){0.f, 0.f, 0.f, 0.f};

    const int fr = lane & 15;
    const int fk = (lane >> 4) * 8;

    const int kt0   = z * kt_per;
    const int ktEnd = kt0 + kt_per;

    float4 rA[4], rB[4];   // A f32 staging regs (fully unrolled -> static idx)

#define STAGE_B(buf, k0)                                                                \
    {                                                                                   \
        _Pragma("unroll")                                                               \
        for (int r = 0; r < 4; ++r) {                                                   \
            const _Float16* gb = gB0 + (size_t)(r * 8) * FEAT + (k0);                   \
            unsigned short* lb = &Bs[buf][(wave * 4 + r) * 512 + srow * 64 + skcol];    \
            __builtin_amdgcn_global_load_lds((const __attribute__((address_space(1))) uint32_t*)gb, \
                                             (__attribute__((address_space(3))) uint32_t*)lb, 16, 0, 0); \
        }                                                                               \
    }
#define LOAD_A(k0)                                                                      \
    {                                                                                   \
        _Pragma("unroll")                                                               \
        for (int r = 0; r < 4; ++r) {                                                   \
            const float* gx = gX0 + (size_t)(r * 8) * FEAT + (k0);                      \
            rA[r] = *(const float4*)gx;                                                 \
            rB[r] = *(const float4*)(gx + 4);                                           \
        }                                                                               \
    }
#define WRITE_A(buf)                                                                    \
    {                                                                                   \
        _Pragma("unroll")                                                               \
        for (int r = 0; r < 4; ++r) {                                                   \
            uint4 w = { pkrtz_u32(rA[r].x, rA[r].y), pkrtz_u32(rA[r].z, rA[r].w),       \
                        pkrtz_u32(rB[r].x, rB[r].y), pkrtz_u32(rB[r].z, rB[r].w) };     \
            *(uint4*)&As[buf][(wave * 4 + r) * 512 + srow * 64 + skcol] = w;            \
        }                                                                               \
    }

    // Prologue: tile kt0 into buf 0.
    STAGE_B(0, kt0 * BK);
    LOAD_A(kt0 * BK);
    asm volatile("s_waitcnt vmcnt(0)" ::: "memory");
    WRITE_A(0);
    __syncthreads();

    for (int kt = kt0; kt < ktEnd; ++kt) {
        const int cur = (kt - kt0) & 1;
        const bool more = (kt + 1 < ktEnd);
        if (more) {
            STAGE_B(cur ^ 1, (kt + 1) * BK);   // 4 gload_lds (counted in vmcnt)
            LOAD_A((kt + 1) * BK);             // 8 global_load_dwordx4 -> regs
        }

        #pragma unroll
        for (int kk = 0; kk < BK; kk += 32) {
            f16x8 av[4], bv[4];
            #pragma unroll
            for (int t = 0; t < 4; ++t)
                av[t] = *(const f16x8*)&As[cur][(wm + t * 16 + fr) * BK + kk + fk];
            #pragma unroll
            for (int t = 0; t < 4; ++t)
                bv[t] = *(const f16x8*)&Bs[cur][(wn + t * 16 + fr) * BK + kk + fk];
            #pragma unroll
            for (int i = 0; i < 4; ++i)
                #pragma unroll
                for (int j = 0; j < 4; ++j)
                    acc[i][j] = __builtin_amdgcn_mfma_f32_16x16x32_f16(av[i], bv[j], acc[i][j], 0, 0, 0);
        }

        if (more) {
            asm volatile("s_waitcnt vmcnt(0)" ::: "memory");  // A regs + B-in-LDS landed (overlapped MFMA)
            WRITE_A(cur ^ 1);                                 // nxt buffer: published by barrier below
        }
        __syncthreads();
    }
#undef STAGE_B
#undef LOAD_A
#undef WRITE_A

    const int crow0 = bm * BM + wm + (lane >> 4) * 4;
    const int ccol0 = bn * BN + wn + (lane & 15);
    #pragma unroll
    for (int i = 0; i < 4; ++i)
        #pragma unroll
        for (int j = 0; j < 4; ++j)
            #pragma unroll
            for (int r = 0; r < 4; ++r)
                C[(size_t)(crow0 + i * 16 + r) * NCOL + ccol0 + j * 16] = (_Float16)acc[i][j][r];
}

// ------- Kernel 3: pairwise L1+exp2, SYMMETRIC (each pair computed once) --
// R8 version verbatim.
#define JWAVES 4
__global__ __launch_bounds__(256, 8) void k_pairwise(const _Float16* __restrict__ Mp,
                                                     int nparts,
                                                     float* __restrict__ Os) {
    __shared__ _Float16 rowl[NCOL];          // 4KB (one row, lg2e-prescaled)
    __shared__ float    part[JWAVES][2][64]; // 2KB
    const int b  = blockIdx.x;
    const int t  = threadIdx.x;
    const int w  = t >> 6;                   // wave id (o-chunk)
    const int tl = t & 63;

    const size_t PART  = (size_t)B_ROWS * NCOL;
    const size_t gbase = (size_t)b * NCOL;
    const f16x2 lg2e = { (_Float16)1.44269504f, (_Float16)1.44269504f };

    {
        f16x8 v = *(const f16x8*)(Mp + gbase + (size_t)t * 8);
        for (int z = 1; z < nparts; ++z)
            v = v + *(const f16x8*)(Mp + (size_t)z * PART + gbase + (size_t)t * 8);
        f16x2 a0 = { v[0], v[1] }, a1 = { v[2], v[3] }, a2 = { v[4], v[5] }, a3 = { v[6], v[7] };
        a0 *= lg2e; a1 *= lg2e; a2 *= lg2e; a3 *= lg2e;
        uint4 wr = { __builtin_bit_cast(unsigned, a0), __builtin_bit_cast(unsigned, a1),
                     __builtin_bit_cast(unsigned, a2), __builtin_bit_cast(unsigned, a3) };
        *(uint4*)&rowl[t * 8] = wr;
    }
    __syncthreads();

    const uint4 uaA = *(const uint4*)&rowl[tl * ND];
    const uint4 uaB = *(const uint4*)&rowl[tl * ND + 8];
    const uint4 ubA = *(const uint4*)&rowl[(tl + 64) * ND];
    const uint4 ubB = *(const uint4*)&rowl[(tl + 64) * ND + 8];
    const f16x2 ma0 = u2h(uaA.x), ma1 = u2h(uaA.y), ma2 = u2h(uaA.z), ma3 = u2h(uaA.w);
    const f16x2 ma4 = u2h(uaB.x), ma5 = u2h(uaB.y), ma6 = u2h(uaB.z), ma7 = u2h(uaB.w);
    const f16x2 mb0 = u2h(ubA.x), mb1 = u2h(ubA.y), mb2 = u2h(ubA.z), mb3 = u2h(ubA.w);
    const f16x2 mb4 = u2h(ubB.x), mb5 = u2h(ubB.y), mb6 = u2h(ubB.z), mb7 = u2h(ubB.w);

    float acc0 = 0.f, acc1 = 0.f;
    #pragma unroll 2
    for (int jj = 0; jj < 16; ++jj) {
        const int o  = w * 16 + 1 + jj;          // wave-uniform, 1..64
        const int jA = (tl + o) & 127;
        const int jB = jA ^ 64;
        const uint4 va0 = *(const uint4*)&rowl[jA * ND];
        const uint4 va1 = *(const uint4*)&rowl[jA * ND + 8];
        const uint4 vb0 = *(const uint4*)&rowl[jB * ND];
        const uint4 vb1 = *(const uint4*)&rowl[jB * ND + 8];

        float eA, eB;
        {
            f16x2 s01 = (absdiff2(ma0, u2h(va0.x)) + absdiff2(ma1, u2h(va0.y)))
                      + (absdiff2(ma2, u2h(va0.z)) + absdiff2(ma3, u2h(va0.w)));
            f16x2 s23 = (absdiff2(ma4, u2h(va1.x)) + absdiff2(ma5, u2h(va1.y)))
                      + (absdiff2(ma6, u2h(va1.z)) + absdiff2(ma7, u2h(va1.w)));
            f16x2 s = s01 + s23;
            eA = __builtin_amdgcn_exp2f(-(float)(_Float16)(s[0] + s[1]));
        }
        {
            f16x2 s01 = (absdiff2(mb0, u2h(vb0.x)) + absdiff2(mb1, u2h(vb0.y)))
                      + (absdiff2(mb2, u2h(vb0.z)) + absdiff2(mb3, u2h(vb0.w)));
            f16x2 s23 = (absdiff2(mb4, u2h(vb1.x)) + absdiff2(mb5, u2h(vb1.y)))
                      + (absdiff2(mb6, u2h(vb1.z)) + absdiff2(mb7, u2h(vb1.w)));
            f16x2 s = s01 + s23;
            eB = __builtin_amdgcn_exp2f(-(float)(_Float16)(s[0] + s[1]));
        }

        if (o < 64) {
            const int src = (tl - o) & 63;
            const float eA2 = __shfl(eA, src, 64);
            const float eB2 = __shfl(eB, src, 64);
            const bool wrap = tl < o;            // receiver-side wrap test
            acc0 += eA + (wrap ? eB2 : eA2);
            acc1 += eB + (wrap ? eA2 : eB2);
        } else {                                 // o == 64: pair {tl, tl+64}
            acc0 += eA;
            acc1 += eB;
        }
    }
    part[w][0][tl] = acc0;
    part[w][1][tl] = acc1;
    __syncthreads();
    if (t < NK) {
        const int h = t >> 6, il = t & 63;
        float s = 1.0f                            // exact diagonal term
                + (part[0][h][il] + part[1][h][il])
                + (part[2][h][il] + part[3][h][il]);
        Os[(size_t)b * NK + t] = s;
    }
}

extern "C" void kernel_launch(void* const* d_in, const int* in_sizes, int n_in,
                              void* d_out, int out_size, void* d_ws, size_t ws_size,
                              hipStream_t stream) {
    const float* x = (const float*)d_in[0];
    const float* W = (const float*)d_in[1];
    float* Os = (float*)d_out;

    char* ws = (char*)d_ws;
    _Float16* Wt = (_Float16*)ws;                                   // 8MB
    _Float16* Mp = (_Float16*)(ws + (size_t)8 * 1024 * 1024);       // 8MB x nsplit

    const size_t MB = (size_t)1024 * 1024;
    const int nsplit = (ws_size >= 24 * MB) ? 2 : 1;   // 512 blocks = 2/CU, one pass

    k_prep<<<4096, 256, 0, stream>>>(W, Wt);

    dim3 gg(NCOL / BN, B_ROWS / BM, nsplit);  // 16 x 16 x nsplit
    k_gemm<<<gg, 256, 0, stream>>>(x, Wt, Mp, (FEAT / BK) / nsplit);

    k_pairwise<<<B_ROWS, 256, 0, stream>>>(Mp, nsplit, Os);
}